// Round 1
// baseline (445.975 us; speedup 1.0000x reference)
//
#include <hip/hip_runtime.h>
#include <hip/hip_bf16.h>

#define NNODE 512
#define DPp 16
#define DNn 16
#define BIO 64
#define TOPO 16
#define KSEL 25
#define HID 8
#define EP (NNODE*DPp)
#define EN (NNODE*DNn)
#define ET (EP+EN)

// ---------------- K1: stable per-node incident edge lists ----------------
// which 0: gp_pos[p][j] = pos_edge[0][e] for e with pos_edge[1][e]==p (stable order)
// which 1: gp_neg      (neg_edge)
// which 2: ph_pos[g][j] = pos_edge[1][e] for e with pos_edge[0][e]==g
// which 3: ph_neg
__global__ __launch_bounds__(256) void k_adj(const int* __restrict__ pos_edge,
                                             const int* __restrict__ neg_edge,
                                             int* __restrict__ gp_pos, int* __restrict__ gp_neg,
                                             int* __restrict__ ph_pos, int* __restrict__ ph_neg)
{
    int tid = blockIdx.x * blockDim.x + threadIdx.x;   // 2048
    int node  = tid & (NNODE - 1);
    int which = tid >> 9;
    const int *key, *val; int *out; int E;
    if      (which == 0) { key = pos_edge + EP; val = pos_edge;      out = gp_pos; E = EP; }
    else if (which == 1) { key = neg_edge + EN; val = neg_edge;      out = gp_neg; E = EN; }
    else if (which == 2) { key = pos_edge;      val = pos_edge + EP; out = ph_pos; E = EP; }
    else                 { key = neg_edge;      val = neg_edge + EN; out = ph_neg; E = EN; }
    int cnt = 0;
    int* dst = out + node * 16;
    for (int e = 0; e < E; e += 4) {
        int4 k4 = *reinterpret_cast<const int4*>(key + e);
        if (k4.x == node) dst[cnt++] = val[e];
        if (k4.y == node) dst[cnt++] = val[e + 1];
        if (k4.z == node) dst[cnt++] = val[e + 2];
        if (k4.w == node) dst[cnt++] = val[e + 3];
    }
}

// ---------------- K2: topo GCN (65 nodes) + stable top-K + const term ----------------
__global__ __launch_bounds__(256) void k_topo(
    const float* __restrict__ tw,  const float* __restrict__ tb,
    const float* __restrict__ pw1, const float* __restrict__ pb1,
    const float* __restrict__ pw2, const float* __restrict__ pb2,
    const float* __restrict__ nw1, const float* __restrict__ nb1,
    const float* __restrict__ nw2, const float* __restrict__ nb2,
    const float* __restrict__ mw1, const float* __restrict__ mb1,
    int* __restrict__ sel_out,      // [2][32] (K used)
    float* __restrict__ const_out)  // [2][HID]
{
    int s = blockIdx.x;     // state 0 or 1
    int t = threadIdx.x;
    __shared__ float cur[65][16];
    __shared__ float hh[65][16];
    __shared__ float acc[65][16];
    __shared__ float sv[64];
    __shared__ int   sel[KSEL];

    int pg = 16 - s;   // == pp
    int ng = 15 + s;   // == nq

    for (int br = 0; br < 2; ++br) {
        int A       = (br == 0) ? pg : ng;        // sources into node 33; also #receiver pheos
        int srcbase = (br == 0) ? 2  : 2 + pg;
        int dstbase = (br == 0) ? 34 : 34 + pg;
        const float* W1 = (br == 0) ? pw1 : nw1;
        const float* B1 = (br == 0) ? pb1 : nb1;
        const float* W2 = (br == 0) ? pw2 : nw2;
        const float* B2 = (br == 0) ? pb2 : nb2;
        float degA = 1.0f + (float)A;
        float rA   = rsqrtf(degA);
        const float r2 = 0.70710678118654752f;

        // layer 1: hh = onehot(labels) @ W1  ->  row select
        for (int i = t; i < 65 * 16; i += 256) {
            int v = i >> 4, f = i & 15;
            int lab;
            if (v <= 1)            lab = 0;
            else if (v < 2 + pg)   lab = 2;
            else if (v < 33)       lab = 4;
            else if (v == 33)      lab = 1;
            else if (v < 34 + pg)  lab = 3;
            else                   lab = 5;
            hh[v][f] = W1[lab * 16 + f];
        }
        __syncthreads();
        // aggregate (GCN norm, analytic degrees) + bias + tanh -> cur
        for (int i = t; i < 65 * 16; i += 256) {
            int v = i >> 4, f = i & 15;
            float dv = (v == 33) ? degA : ((v >= dstbase && v < dstbase + A) ? 2.0f : 1.0f);
            float val = hh[v][f] / dv + B1[f];
            if (v == 33) {
                float ss = 0.f;
                for (int j = 0; j < A; ++j) ss += hh[srcbase + j][f];
                val += ss * rA;                    // src deg==1
            } else if (v >= dstbase && v < dstbase + A) {
                val += hh[1][f] * r2;              // node1 deg==1, dst deg==2
            }
            cur[v][f] = tanhf(val);
        }
        __syncthreads();
        // layer 2 matmul: hh = cur @ W2
        for (int i = t; i < 65 * 16; i += 256) {
            int v = i >> 4, f = i & 15;
            float sum = 0.f;
            for (int c = 0; c < 16; ++c) sum += cur[v][c] * W2[c * 16 + f];
            hh[v][f] = sum;
        }
        __syncthreads();
        // aggregate + tanh, accumulate branches
        for (int i = t; i < 65 * 16; i += 256) {
            int v = i >> 4, f = i & 15;
            float dv = (v == 33) ? degA : ((v >= dstbase && v < dstbase + A) ? 2.0f : 1.0f);
            float val = hh[v][f] / dv + B2[f];
            if (v == 33) {
                float ss = 0.f;
                for (int j = 0; j < A; ++j) ss += hh[srcbase + j][f];
                val += ss * rA;
            } else if (v >= dstbase && v < dstbase + A) {
                val += hh[1][f] * r2;
            }
            val = tanhf(val);
            if (br == 0) acc[v][f] = val; else acc[v][f] += val;
        }
        __syncthreads();
    }

    // SortPooling scores over rows 1..64
    if (t < 64) {
        float x = tb[0];
        for (int f = 0; f < 16; ++f) x += acc[t + 1][f] * tw[f];
        sv[t] = x;
    }
    __syncthreads();
    // stable top-K: rank = #{strictly greater} + #{equal with smaller index}
    if (t < 64) {
        float mine = sv[t];
        int rank = 0;
        for (int m = 0; m < 64; ++m) {
            float o = sv[m];
            if (o > mine || (o == mine && m < t)) ++rank;
        }
        if (rank < KSEL) { sel[rank] = t; sel_out[s * 32 + rank] = t; }
    }
    __syncthreads();
    // const term: topo block (cols 0..15 of each selected row) folded with mw1
    if (t < HID) {
        float cst = mb1[t];
        for (int k = 0; k < KSEL; ++k) {
            int m = sel[k];
            for (int c = 0; c < 16; ++c)
                cst += acc[m + 1][c] * mw1[(k * 80 + c) * 8 + t];
        }
        const_out[s * HID + t] = cst;
    }
}

// ---------------- K3: per-node fp / fg (8-vectors) ----------------
__global__ __launch_bounds__(64) void k_nodefh(
    const float* __restrict__ gene_feat, const float* __restrict__ pheo_feat,
    const float* __restrict__ mw1,
    const int* __restrict__ gp_pos, const int* __restrict__ gp_neg,
    const int* __restrict__ ph_pos, const int* __restrict__ ph_neg,
    const int* __restrict__ sel,    // [2][32]
    float* __restrict__ fp, float* __restrict__ fg)   // each [2][512][8]
{
    int b    = blockIdx.x;          // 2048 = 2 states * 2 sides * 512 nodes
    int node = b & (NNODE - 1);
    int side = (b >> 9) & 1;        // 0: p-side (fp), 1: g-side (fg)
    int s    = b >> 10;
    int t = threadIdx.x;
    int h = t & 7, chunk = t >> 3;  // 8 h x 8 chunks of 8 columns

    float accv = 0.f;
    for (int k = 0; k < KSEL; ++k) {
        int m = sel[s * 32 + k];
        const float* feat;
        if (side == 0) {
            if (m >= 32) continue;
            int gid = (m < 16) ? gp_pos[node * 16 + m] : gp_neg[node * 16 + m - 16];
            feat = gene_feat + gid * BIO;
        } else {
            if (m < 32) continue;
            int mm = m - 32;
            int pid = (mm < 16) ? ph_pos[node * 16 + mm] : ph_neg[node * 16 + mm - 16];
            feat = pheo_feat + pid * BIO;
        }
        const float* w = mw1 + (k * 80 + 16 + chunk * 8) * 8 + h;
        #pragma unroll
        for (int i = 0; i < 8; ++i) accv += feat[chunk * 8 + i] * w[i * 8];
    }
    // reduce over the 8 chunks (lanes differing in bits 3..5)
    accv += __shfl_xor(accv, 8);
    accv += __shfl_xor(accv, 16);
    accv += __shfl_xor(accv, 32);
    if (t < 8) {
        float* dstp = (side == 0 ? fp : fg) + (s * NNODE + node) * 8 + t;
        *dstp = accv;
    }
}

// ---------------- K4: per-edge score + loss partials ----------------
__device__ inline float softplusf(float x) {
    return x > 0.f ? x + log1pf(expf(-x)) : log1pf(expf(x));
}

__global__ __launch_bounds__(256) void k_edge(
    const int* __restrict__ pos_edge, const int* __restrict__ neg_edge,
    const float* __restrict__ cst, const float* __restrict__ fp, const float* __restrict__ fg,
    const float* __restrict__ mw2, const float* __restrict__ mb2,
    float pw, float* __restrict__ out, float* __restrict__ partial)
{
    int e = blockIdx.x * 256 + threadIdx.x;   // grid covers exactly ET
    int g, p, s;
    if (e < EP) { g = pos_edge[e]; p = pos_edge[EP + e]; s = 1; }
    else { int i = e - EP; g = neg_edge[i]; p = neg_edge[EN + i]; s = 0; }
    const float* cp  = cst + s * 8;
    const float* fpp = fp + (s * NNODE + p) * 8;
    const float* fgg = fg + (s * NNODE + g) * 8;
    float sc = mb2[0];
    #pragma unroll
    for (int h = 0; h < HID; ++h) {
        float v = cp[h] + fpp[h] + fgg[h];
        v = v > 0.f ? v : 0.f;
        sc += v * mw2[h];
    }
    out[1 + e] = sc;
    float y = (e < EP) ? 1.f : 0.f;
    out[1 + ET + e] = y;
    float term = ((e < EP) ? pw * softplusf(-sc) : softplusf(sc)) * (1.0f / (float)ET);

    // deterministic block reduction
    float v = term;
    for (int off = 32; off; off >>= 1) v += __shfl_down(v, off);
    __shared__ float wsum[4];
    if ((threadIdx.x & 63) == 0) wsum[threadIdx.x >> 6] = v;
    __syncthreads();
    if (threadIdx.x == 0) partial[blockIdx.x] = (wsum[0] + wsum[1]) + (wsum[2] + wsum[3]);
}

// ---------------- K5: deterministic loss sum ----------------
__global__ __launch_bounds__(64) void k_reduce(const float* __restrict__ partial,
                                               float* __restrict__ out)
{
    float v = partial[threadIdx.x];
    for (int off = 32; off; off >>= 1) v += __shfl_down(v, off);
    if (threadIdx.x == 0) out[0] = v;
}

extern "C" void kernel_launch(void* const* d_in, const int* in_sizes, int n_in,
                              void* d_out, int out_size, void* d_ws, size_t ws_size,
                              hipStream_t stream)
{
    const int*   pos_edge  = (const int*)  d_in[0];
    const int*   neg_edge  = (const int*)  d_in[1];
    const float* gene_feat = (const float*)d_in[2];
    const float* pheo_feat = (const float*)d_in[3];
    const float* tw  = (const float*)d_in[4];
    const float* tb  = (const float*)d_in[5];
    const float* pw1 = (const float*)d_in[6];
    const float* pb1 = (const float*)d_in[7];
    const float* pw2 = (const float*)d_in[8];
    const float* pb2 = (const float*)d_in[9];
    const float* nw1 = (const float*)d_in[10];
    const float* nb1 = (const float*)d_in[11];
    const float* nw2 = (const float*)d_in[12];
    const float* nb2 = (const float*)d_in[13];
    const float* mw1 = (const float*)d_in[14];
    const float* mb1 = (const float*)d_in[15];
    const float* mw2 = (const float*)d_in[16];
    const float* mb2 = (const float*)d_in[17];
    float* out = (float*)d_out;

    char* ws = (char*)d_ws;
    int*   gp_pos  = (int*)(ws);
    int*   gp_neg  = (int*)(ws + 32768);
    int*   ph_pos  = (int*)(ws + 65536);
    int*   ph_neg  = (int*)(ws + 98304);
    int*   sel     = (int*)(ws + 131072);            // [2][32]
    float* cst     = (float*)(ws + 131072 + 256);    // [2][8]
    float* fp      = (float*)(ws + 131072 + 512);            // [2][512][8]
    float* fg      = (float*)(ws + 131072 + 512 + 32768);    // [2][512][8]
    float* partial = (float*)(ws + 131072 + 512 + 65536);    // [64]

    k_adj<<<dim3(8), dim3(256), 0, stream>>>(pos_edge, neg_edge, gp_pos, gp_neg, ph_pos, ph_neg);
    k_topo<<<dim3(2), dim3(256), 0, stream>>>(tw, tb, pw1, pb1, pw2, pb2,
                                              nw1, nb1, nw2, nb2, mw1, mb1, sel, cst);
    k_nodefh<<<dim3(2048), dim3(64), 0, stream>>>(gene_feat, pheo_feat, mw1,
                                                  gp_pos, gp_neg, ph_pos, ph_neg, sel, fp, fg);
    float pwv = (float)(in_sizes[1] / 2) / (float)(in_sizes[0] / 2);
    k_edge<<<dim3(ET / 256), dim3(256), 0, stream>>>(pos_edge, neg_edge, cst, fp, fg,
                                                     mw2, mb2, pwv, out, partial);
    k_reduce<<<dim3(1), dim3(64), 0, stream>>>(partial, out);
}

// Round 2
// 45.875 us; speedup vs baseline: 9.7216x; 9.7216x over previous
//
#include <hip/hip_runtime.h>
#include <hip/hip_bf16.h>

#define NNODE 512
#define DPp 16
#define DNn 16
#define BIO 64
#define TOPO 16
#define KSEL 25
#define HID 8
#define EP (NNODE*DPp)
#define EN (NNODE*DNn)
#define ET (EP+EN)
#define NCHUNK 32           // 8192 / 256
#define CHUNK 256

// ---------------- K1a: per-chunk histograms + local stable ranks ----------------
// which 0: keys=pos_edge[1], vals=pos_edge[0] -> gp_pos
// which 1: keys=neg_edge[1], vals=neg_edge[0] -> gp_neg
// which 2: keys=pos_edge[0], vals=pos_edge[1] -> ph_pos
// which 3: keys=neg_edge[0], vals=neg_edge[1] -> ph_neg
__global__ __launch_bounds__(256) void k_adj_a(const int* __restrict__ pos_edge,
                                               const int* __restrict__ neg_edge,
                                               int* __restrict__ cnt,    // [4][NCHUNK][NNODE]
                                               int* __restrict__ lrank)  // [4][EP]
{
    int which = blockIdx.x, chunk = blockIdx.y, t = threadIdx.x;
    const int* key;
    if      (which == 0) key = pos_edge + EP;
    else if (which == 1) key = neg_edge + EN;
    else if (which == 2) key = pos_edge;
    else                 key = neg_edge;
    int e = chunk * CHUNK + t;

    __shared__ int skey[CHUNK];
    __shared__ int shist[NNODE];
    shist[t] = 0; shist[t + 256] = 0;
    __syncthreads();
    int k = key[e];
    skey[t] = k;
    atomicAdd(&shist[k], 1);
    __syncthreads();
    int r = 0;
    for (int i = 0; i < t; ++i) r += (skey[i] == k);
    lrank[which * EP + e] = r;
    int base = (which * NCHUNK + chunk) * NNODE;
    cnt[base + t] = shist[t];
    cnt[base + t + 256] = shist[t + 256];
}

// ---------------- K1b: scatter to per-node lists ----------------
__global__ __launch_bounds__(256) void k_adj_b(const int* __restrict__ pos_edge,
                                               const int* __restrict__ neg_edge,
                                               const int* __restrict__ cnt,
                                               const int* __restrict__ lrank,
                                               int* __restrict__ gp_pos, int* __restrict__ gp_neg,
                                               int* __restrict__ ph_pos, int* __restrict__ ph_neg)
{
    int which = blockIdx.x, chunk = blockIdx.y, t = threadIdx.x;
    const int *key, *val; int* out;
    if      (which == 0) { key = pos_edge + EP; val = pos_edge;      out = gp_pos; }
    else if (which == 1) { key = neg_edge + EN; val = neg_edge;      out = gp_neg; }
    else if (which == 2) { key = pos_edge;      val = pos_edge + EP; out = ph_pos; }
    else                 { key = neg_edge;      val = neg_edge + EN; out = ph_neg; }
    int e = chunk * CHUNK + t;
    int k = key[e];
    int pos = lrank[which * EP + e];
    for (int c = 0; c < chunk; ++c) pos += cnt[(which * NCHUNK + c) * NNODE + k];
    out[k * 16 + pos] = val[e];
}

// ---------------- K2: topo GCN (65 nodes) + stable top-K + const term ----------------
__global__ __launch_bounds__(256) void k_topo(
    const float* __restrict__ tw,  const float* __restrict__ tb,
    const float* __restrict__ pw1, const float* __restrict__ pb1,
    const float* __restrict__ pw2, const float* __restrict__ pb2,
    const float* __restrict__ nw1, const float* __restrict__ nb1,
    const float* __restrict__ nw2, const float* __restrict__ nb2,
    const float* __restrict__ mw1, const float* __restrict__ mb1,
    int* __restrict__ sel_out,      // [2][32] (K used)
    float* __restrict__ const_out)  // [2][HID]
{
    int s = blockIdx.x;     // state 0 or 1
    int t = threadIdx.x;
    __shared__ float cur[65][16];
    __shared__ float hh[65][16];
    __shared__ float acc[65][16];
    __shared__ float sv[64];
    __shared__ int   sel[KSEL];

    int pg = 16 - s;   // == pp
    int ng = 15 + s;   // == nq

    for (int br = 0; br < 2; ++br) {
        int A       = (br == 0) ? pg : ng;
        int srcbase = (br == 0) ? 2  : 2 + pg;
        int dstbase = (br == 0) ? 34 : 34 + pg;
        const float* W1 = (br == 0) ? pw1 : nw1;
        const float* B1 = (br == 0) ? pb1 : nb1;
        const float* W2 = (br == 0) ? pw2 : nw2;
        const float* B2 = (br == 0) ? pb2 : nb2;
        float degA = 1.0f + (float)A;
        float rA   = rsqrtf(degA);
        const float r2 = 0.70710678118654752f;

        for (int i = t; i < 65 * 16; i += 256) {
            int v = i >> 4, f = i & 15;
            int lab;
            if (v <= 1)            lab = 0;
            else if (v < 2 + pg)   lab = 2;
            else if (v < 33)       lab = 4;
            else if (v == 33)      lab = 1;
            else if (v < 34 + pg)  lab = 3;
            else                   lab = 5;
            hh[v][f] = W1[lab * 16 + f];
        }
        __syncthreads();
        for (int i = t; i < 65 * 16; i += 256) {
            int v = i >> 4, f = i & 15;
            float dv = (v == 33) ? degA : ((v >= dstbase && v < dstbase + A) ? 2.0f : 1.0f);
            float val = hh[v][f] / dv + B1[f];
            if (v == 33) {
                float ss = 0.f;
                for (int j = 0; j < A; ++j) ss += hh[srcbase + j][f];
                val += ss * rA;
            } else if (v >= dstbase && v < dstbase + A) {
                val += hh[1][f] * r2;
            }
            cur[v][f] = tanhf(val);
        }
        __syncthreads();
        for (int i = t; i < 65 * 16; i += 256) {
            int v = i >> 4, f = i & 15;
            float sum = 0.f;
            for (int c = 0; c < 16; ++c) sum += cur[v][c] * W2[c * 16 + f];
            hh[v][f] = sum;
        }
        __syncthreads();
        for (int i = t; i < 65 * 16; i += 256) {
            int v = i >> 4, f = i & 15;
            float dv = (v == 33) ? degA : ((v >= dstbase && v < dstbase + A) ? 2.0f : 1.0f);
            float val = hh[v][f] / dv + B2[f];
            if (v == 33) {
                float ss = 0.f;
                for (int j = 0; j < A; ++j) ss += hh[srcbase + j][f];
                val += ss * rA;
            } else if (v >= dstbase && v < dstbase + A) {
                val += hh[1][f] * r2;
            }
            val = tanhf(val);
            if (br == 0) acc[v][f] = val; else acc[v][f] += val;
        }
        __syncthreads();
    }

    if (t < 64) {
        float x = tb[0];
        for (int f = 0; f < 16; ++f) x += acc[t + 1][f] * tw[f];
        sv[t] = x;
    }
    __syncthreads();
    if (t < 64) {
        float mine = sv[t];
        int rank = 0;
        for (int m = 0; m < 64; ++m) {
            float o = sv[m];
            if (o > mine || (o == mine && m < t)) ++rank;
        }
        if (rank < KSEL) { sel[rank] = t; sel_out[s * 32 + rank] = t; }
    }
    __syncthreads();
    if (t < HID) {
        float cst = mb1[t];
        for (int k = 0; k < KSEL; ++k) {
            int m = sel[k];
            for (int c = 0; c < 16; ++c)
                cst += acc[m + 1][c] * mw1[(k * 80 + c) * 8 + t];
        }
        const_out[s * HID + t] = cst;
    }
}

// ---------------- K3: per-node fp / fg (8-vectors) ----------------
__global__ __launch_bounds__(64) void k_nodefh(
    const float* __restrict__ gene_feat, const float* __restrict__ pheo_feat,
    const float* __restrict__ mw1,
    const int* __restrict__ gp_pos, const int* __restrict__ gp_neg,
    const int* __restrict__ ph_pos, const int* __restrict__ ph_neg,
    const int* __restrict__ sel,    // [2][32]
    float* __restrict__ fp, float* __restrict__ fg)   // each [2][512][8]
{
    int b    = blockIdx.x;          // 2048 = 2 states * 2 sides * 512 nodes
    int node = b & (NNODE - 1);
    int side = (b >> 9) & 1;
    int s    = b >> 10;
    int t = threadIdx.x;
    int h = t & 7, chunk = t >> 3;

    float accv = 0.f;
    for (int k = 0; k < KSEL; ++k) {
        int m = sel[s * 32 + k];
        const float* feat;
        if (side == 0) {
            if (m >= 32) continue;
            int gid = (m < 16) ? gp_pos[node * 16 + m] : gp_neg[node * 16 + m - 16];
            feat = gene_feat + gid * BIO;
        } else {
            if (m < 32) continue;
            int mm = m - 32;
            int pid = (mm < 16) ? ph_pos[node * 16 + mm] : ph_neg[node * 16 + mm - 16];
            feat = pheo_feat + pid * BIO;
        }
        const float* w = mw1 + (k * 80 + 16 + chunk * 8) * 8 + h;
        #pragma unroll
        for (int i = 0; i < 8; ++i) accv += feat[chunk * 8 + i] * w[i * 8];
    }
    accv += __shfl_xor(accv, 8);
    accv += __shfl_xor(accv, 16);
    accv += __shfl_xor(accv, 32);
    if (t < 8) {
        float* dstp = (side == 0 ? fp : fg) + (s * NNODE + node) * 8 + t;
        *dstp = accv;
    }
}

// ---------------- K4: per-edge score + loss partials ----------------
__device__ inline float softplusf(float x) {
    return x > 0.f ? x + log1pf(expf(-x)) : log1pf(expf(x));
}

__global__ __launch_bounds__(256) void k_edge(
    const int* __restrict__ pos_edge, const int* __restrict__ neg_edge,
    const float* __restrict__ cst, const float* __restrict__ fp, const float* __restrict__ fg,
    const float* __restrict__ mw2, const float* __restrict__ mb2,
    float pw, float* __restrict__ out, float* __restrict__ partial)
{
    int e = blockIdx.x * 256 + threadIdx.x;
    int g, p, s;
    if (e < EP) { g = pos_edge[e]; p = pos_edge[EP + e]; s = 1; }
    else { int i = e - EP; g = neg_edge[i]; p = neg_edge[EN + i]; s = 0; }
    const float* cp  = cst + s * 8;
    const float* fpp = fp + (s * NNODE + p) * 8;
    const float* fgg = fg + (s * NNODE + g) * 8;
    float sc = mb2[0];
    #pragma unroll
    for (int h = 0; h < HID; ++h) {
        float v = cp[h] + fpp[h] + fgg[h];
        v = v > 0.f ? v : 0.f;
        sc += v * mw2[h];
    }
    out[1 + e] = sc;
    float y = (e < EP) ? 1.f : 0.f;
    out[1 + ET + e] = y;
    float term = ((e < EP) ? pw * softplusf(-sc) : softplusf(sc)) * (1.0f / (float)ET);

    float v = term;
    for (int off = 32; off; off >>= 1) v += __shfl_down(v, off);
    __shared__ float wsum[4];
    if ((threadIdx.x & 63) == 0) wsum[threadIdx.x >> 6] = v;
    __syncthreads();
    if (threadIdx.x == 0) partial[blockIdx.x] = (wsum[0] + wsum[1]) + (wsum[2] + wsum[3]);
}

// ---------------- K5: deterministic loss sum ----------------
__global__ __launch_bounds__(64) void k_reduce(const float* __restrict__ partial,
                                               float* __restrict__ out)
{
    float v = partial[threadIdx.x];
    for (int off = 32; off; off >>= 1) v += __shfl_down(v, off);
    if (threadIdx.x == 0) out[0] = v;
}

extern "C" void kernel_launch(void* const* d_in, const int* in_sizes, int n_in,
                              void* d_out, int out_size, void* d_ws, size_t ws_size,
                              hipStream_t stream)
{
    const int*   pos_edge  = (const int*)  d_in[0];
    const int*   neg_edge  = (const int*)  d_in[1];
    const float* gene_feat = (const float*)d_in[2];
    const float* pheo_feat = (const float*)d_in[3];
    const float* tw  = (const float*)d_in[4];
    const float* tb  = (const float*)d_in[5];
    const float* pw1 = (const float*)d_in[6];
    const float* pb1 = (const float*)d_in[7];
    const float* pw2 = (const float*)d_in[8];
    const float* pb2 = (const float*)d_in[9];
    const float* nw1 = (const float*)d_in[10];
    const float* nb1 = (const float*)d_in[11];
    const float* nw2 = (const float*)d_in[12];
    const float* nb2 = (const float*)d_in[13];
    const float* mw1 = (const float*)d_in[14];
    const float* mb1 = (const float*)d_in[15];
    const float* mw2 = (const float*)d_in[16];
    const float* mb2 = (const float*)d_in[17];
    float* out = (float*)d_out;

    char* ws = (char*)d_ws;
    int*   gp_pos  = (int*)(ws);
    int*   gp_neg  = (int*)(ws + 32768);
    int*   ph_pos  = (int*)(ws + 65536);
    int*   ph_neg  = (int*)(ws + 98304);
    int*   sel     = (int*)(ws + 131072);            // [2][32]
    float* cst     = (float*)(ws + 131328);          // [2][8]
    float* fp      = (float*)(ws + 131584);          // [2][512][8]
    float* fg      = (float*)(ws + 164352);          // [2][512][8]
    float* partial = (float*)(ws + 197120);          // [64]
    int*   cnt     = (int*)(ws + 197632);            // [4][32][512]
    int*   lrank   = (int*)(ws + 197632 + 262144);   // [4][8192]

    k_adj_a<<<dim3(4, NCHUNK), dim3(256), 0, stream>>>(pos_edge, neg_edge, cnt, lrank);
    k_adj_b<<<dim3(4, NCHUNK), dim3(256), 0, stream>>>(pos_edge, neg_edge, cnt, lrank,
                                                       gp_pos, gp_neg, ph_pos, ph_neg);
    k_topo<<<dim3(2), dim3(256), 0, stream>>>(tw, tb, pw1, pb1, pw2, pb2,
                                              nw1, nb1, nw2, nb2, mw1, mb1, sel, cst);
    k_nodefh<<<dim3(2048), dim3(64), 0, stream>>>(gene_feat, pheo_feat, mw1,
                                                  gp_pos, gp_neg, ph_pos, ph_neg, sel, fp, fg);
    float pwv = (float)(in_sizes[1] / 2) / (float)(in_sizes[0] / 2);
    k_edge<<<dim3(ET / 256), dim3(256), 0, stream>>>(pos_edge, neg_edge, cst, fp, fg,
                                                     mw2, mb2, pwv, out, partial);
    k_reduce<<<dim3(1), dim3(64), 0, stream>>>(partial, out);
}